// Round 1
// baseline (2221.709 us; speedup 1.0000x reference)
//
#include <hip/hip_runtime.h>

#define D 128

// ---------------------------------------------------------------------------
// Kernel 1: W = 0.95 I - A^T A + B - B^T ;  Mm = 2 I - W   (both 128x128)
// grid=128 (row i), block=128 (col j). A[k*D+i] is block-uniform -> s_loads.
// ---------------------------------------------------------------------------
__global__ void wmat_kernel(const float* __restrict__ A, const float* __restrict__ B,
                            float* __restrict__ W, float* __restrict__ Mm) {
    const int i = blockIdx.x;
    const int j = threadIdx.x;
    float s = 0.f;
#pragma unroll 8
    for (int k = 0; k < D; ++k) s = fmaf(A[k * D + i], A[k * D + j], s);
    const float diag = (i == j) ? 1.f : 0.f;
    const float w = 0.95f * diag - s + B[i * D + j] - B[j * D + i];
    W[i * D + j] = w;
    Mm[i * D + j] = 2.f * diag - w;
}

// ---------------------------------------------------------------------------
// Kernel 2: Winv = Mm^{-1} via Gauss-Jordan, augmented [Mm | I] in REGISTERS.
// 1024 threads: thread t owns column c = t&255, rows r0..r0+31 (rb = t>>8).
// 32 aug entries per thread, statically indexed (rule #20). Mm has PD
// symmetric part (>=1.05 I) so no pivoting required.
// ---------------------------------------------------------------------------
__global__ __launch_bounds__(1024) void inv_kernel(const float* __restrict__ Mm,
                                                   float* __restrict__ Winv) {
    __shared__ float rowbuf[2 * D];
    __shared__ float colbuf[D];
    const int t = threadIdx.x;
    const int c = t & 255;
    const int rb = t >> 8;
    const int r0 = rb * 32;
    float aug[32];
#pragma unroll
    for (int rr = 0; rr < 32; ++rr) {
        const int r = r0 + rr;
        aug[rr] = (c < D) ? Mm[r * D + c] : ((c - D == r) ? 1.f : 0.f);
    }
    for (int k = 0; k < D; ++k) {
        // owners publish pre-update pivot row and pivot column
        float rv = 0.f;
#pragma unroll
        for (int rr = 0; rr < 32; ++rr)
            if (rr == (k & 31)) rv = aug[rr];
        if (rb == (k >> 5)) rowbuf[c] = rv;
        if (c == k) {
#pragma unroll
            for (int rr = 0; rr < 32; ++rr) colbuf[r0 + rr] = aug[rr];
        }
        __syncthreads();
        const float invp = 1.f / rowbuf[k];
        const float pr = rowbuf[c] * invp;  // scaled pivot-row entry, my column
#pragma unroll
        for (int rr = 0; rr < 32; ++rr) {
            const int r = r0 + rr;
            aug[rr] = (r == k) ? pr : fmaf(-colbuf[r], pr, aug[rr]);
        }
        __syncthreads();
    }
    if (c >= D) {
#pragma unroll
        for (int rr = 0; rr < 32; ++rr) Winv[(r0 + rr) * D + (c - D)] = aug[rr];
    }
}

// ---------------------------------------------------------------------------
// Kernel 3: per-row bias + 50 PR iterations + final multiply, one pass.
// 512 threads = 8 waves; wave owns 8 batch rows (state in registers; lane l
// holds element l and l+64 of each 128-vector). Operand matrix staged in LDS
// (Uw -> Winv -> W), XOR-swizzled on 16B granules: logical col c4 of row r
// stored at physical granule (c4 ^ (r&7)) so per-lane row reads spread over
// all 8 bank-quads (conflict-free b128 floor). v-vectors are per-wave LDS
// buffers read as uniform broadcasts. LDS = 64KB + 16KB = 80KB -> 2 blk/CU.
// ---------------------------------------------------------------------------
__global__ __launch_bounds__(512, 4) void mon_main(
    const float* __restrict__ x, const float* __restrict__ Uw,
    const float* __restrict__ ub, const float* __restrict__ Wg,
    const float* __restrict__ Winvg, float* __restrict__ out) {
    __shared__ float4 smat[D * 32];    // 64 KB swizzled 128x128 operand
    __shared__ float4 vbuf4[8 * 8 * 32];  // 16 KB: [wave][row][32 granules]
    float* const vbufF = (float*)vbuf4;

    const int t = threadIdx.x;
    const int w = t >> 6;
    const int l = t & 63;
    const int x0 = l & 7;
    const int rowbase = blockIdx.x * 64 + w * 8;

    auto stage = [&](const float* __restrict__ src) {
        const float4* s4 = (const float4*)src;
#pragma unroll
        for (int i = 0; i < 8; ++i) {
            const int g = t + i * 512;       // linear granule 0..4095
            const int row = g >> 5;
            const int col = g & 31;
            smat[row * 32 + (col ^ (row & 7))] = s4[g];
        }
    };

    float a0[8], a1[8];
    auto matvec = [&]() {
        const float4* vb = vbuf4 + (w * 8) * 32;
        const int base0 = l * 32;
        const int base1 = (l + 64) * 32;
#pragma unroll
        for (int r = 0; r < 8; ++r) { a0[r] = 0.f; a1[r] = 0.f; }
#pragma unroll 4
        for (int c4 = 0; c4 < 32; ++c4) {          // logical 16B granule
            const int off = c4 ^ x0;               // physical (swizzle)
            const float4 w0 = smat[base0 + off];
            const float4 w1 = smat[base1 + off];
#pragma unroll
            for (int r = 0; r < 8; ++r) {
                const float4 v = vb[r * 32 + c4];  // broadcast, imm offset
                a0[r] = fmaf(w0.x, v.x, a0[r]);
                a0[r] = fmaf(w0.y, v.y, a0[r]);
                a0[r] = fmaf(w0.z, v.z, a0[r]);
                a0[r] = fmaf(w0.w, v.w, a0[r]);
                a1[r] = fmaf(w1.x, v.x, a1[r]);
                a1[r] = fmaf(w1.y, v.y, a1[r]);
                a1[r] = fmaf(w1.z, v.z, a1[r]);
                a1[r] = fmaf(w1.w, v.w, a1[r]);
            }
        }
    };

    float* const myv = vbufF + (w * 8) * D;  // row r at myv + r*D

    // ---- Phase A: bias = x @ Uw^T + ub
    stage(Uw);
#pragma unroll
    for (int r = 0; r < 8; ++r) {
        const float* xr = x + (size_t)(rowbase + r) * D;
        myv[r * D + l] = xr[l];
        myv[r * D + l + 64] = xr[l + 64];
    }
    __syncthreads();
    matvec();
    const float ub0 = ub[l], ub1 = ub[l + 64];
    float b0[8], b1[8];
#pragma unroll
    for (int r = 0; r < 8; ++r) { b0[r] = a0[r] + ub0; b1[r] = a1[r] + ub1; }
    __syncthreads();  // all waves done reading Uw

    // ---- Phase B: 50 Peaceman-Rachford iterations (z,u in registers)
    stage(Winvg);
    __syncthreads();
    float z0[8], z1[8], u0[8], u1[8];
#pragma unroll
    for (int r = 0; r < 8; ++r) { z0[r] = 0.f; z1[r] = 0.f; u0[r] = 0.f; u1[r] = 0.f; }
#pragma unroll 1
    for (int it = 0; it < 50; ++it) {
        // v = (2z - u) + bias  (wave-local LDS; per-wave in-order DS pipe)
#pragma unroll
        for (int r = 0; r < 8; ++r) {
            myv[r * D + l] = 2.f * z0[r] - u0[r] + b0[r];
            myv[r * D + l + 64] = 2.f * z1[r] - u1[r] + b1[r];
        }
        matvec();  // a = v @ Winv^T
#pragma unroll
        for (int r = 0; r < 8; ++r) {
            const float u12a = 2.f * z0[r] - u0[r];
            u0[r] = 2.f * a0[r] - u12a;
            z0[r] = fmaxf(u0[r], 0.f);
            const float u12b = 2.f * z1[r] - u1[r];
            u1[r] = 2.f * a1[r] - u12b;
            z1[r] = fmaxf(u1[r], 0.f);
        }
    }
    __syncthreads();  // all waves done reading Winv

    // ---- Phase C: out = relu(bias + z @ W^T)
    stage(Wg);
#pragma unroll
    for (int r = 0; r < 8; ++r) {
        myv[r * D + l] = z0[r];
        myv[r * D + l + 64] = z1[r];
    }
    __syncthreads();
    matvec();
#pragma unroll
    for (int r = 0; r < 8; ++r) {
        float* orow = out + (size_t)(rowbase + r) * D;
        orow[l] = fmaxf(b0[r] + a0[r], 0.f);
        orow[l + 64] = fmaxf(b1[r] + a1[r], 0.f);
    }
}

// ---------------------------------------------------------------------------
extern "C" void kernel_launch(void* const* d_in, const int* in_sizes, int n_in,
                              void* d_out, int out_size, void* d_ws, size_t ws_size,
                              hipStream_t stream) {
    const float* x = (const float*)d_in[0];
    const float* Uw = (const float*)d_in[1];
    const float* ub = (const float*)d_in[2];
    const float* A = (const float*)d_in[3];
    const float* B = (const float*)d_in[4];
    float* out = (float*)d_out;

    float* W = (float*)d_ws;          // 64 KB
    float* Mm = W + D * D;            // 64 KB
    float* Winv = W + 2 * D * D;      // 64 KB   (ws usage: 192 KB total)

    wmat_kernel<<<D, D, 0, stream>>>(A, B, W, Mm);
    inv_kernel<<<1, 1024, 0, stream>>>(Mm, Winv);

    const int batch = in_sizes[0] / D;           // 65536
    mon_main<<<batch / 64, 512, 0, stream>>>(x, Uw, ub, W, Winv, out);
}

// Round 3
// 1298.492 us; speedup vs baseline: 1.7110x; 1.7110x over previous
//
#include <hip/hip_runtime.h>

#define D 128

typedef __attribute__((ext_vector_type(2))) float f32x2;
typedef __attribute__((ext_vector_type(4))) float f32x4;
typedef __attribute__((ext_vector_type(16))) float f32x16;
typedef __attribute__((ext_vector_type(8))) _Float16 f16x8;
typedef __attribute__((ext_vector_type(2))) __fp16 fp16v2;
typedef __attribute__((ext_vector_type(2))) unsigned int u32x2;
typedef __attribute__((ext_vector_type(4))) unsigned int u32x4;

// split f32 pair -> packed f16 hi-pair + lo-pair (hi = RTZ(v), lo = RTZ(v-hi))
__device__ __forceinline__ void split2(float a, float b, unsigned &hi, unsigned &lo) {
  fp16v2 h = __builtin_amdgcn_cvt_pkrtz(a, b);
  float ra = a - (float)h[0];
  float rb = b - (float)h[1];
  fp16v2 lv = __builtin_amdgcn_cvt_pkrtz(ra, rb);
  hi = __builtin_bit_cast(unsigned, h);
  lo = __builtin_bit_cast(unsigned, lv);
}

// per-element {hi f16 | lo f16} packing for LDS-resident f32 values
__device__ __forceinline__ unsigned pack_hl(float a) {
  fp16v2 h = __builtin_amdgcn_cvt_pkrtz(a, 0.f);
  float hf = (float)h[0];
  fp16v2 lv = __builtin_amdgcn_cvt_pkrtz(a - hf, 0.f);
  return (__builtin_bit_cast(unsigned, h) & 0xffffu) | (__builtin_bit_cast(unsigned, lv) << 16);
}
__device__ __forceinline__ float unpack_hl(unsigned u) {
  fp16v2 p = __builtin_bit_cast(fp16v2, u);
  return (float)p[0] + (float)p[1];
}

__device__ __forceinline__ f32x16 mm(u32x4 a, u32x4 b, f32x16 c) {
  return __builtin_amdgcn_mfma_f32_32x32x16_f16(
      __builtin_bit_cast(f16x8, a), __builtin_bit_cast(f16x8, b), c, 0, 0, 0);
}

__device__ __forceinline__ f32x16 zero16() {
  f32x16 z;
#pragma unroll
  for (int e = 0; e < 16; ++e) z[e] = 0.f;
  return z;
}

// ---------------------------------------------------------------------------
// Kernel 1: W = 0.95 I - A^T A + B - B^T ;  Mm = 2 I - W   (both 128x128)
// ---------------------------------------------------------------------------
__global__ void wmat_kernel(const float* __restrict__ A, const float* __restrict__ B,
                            float* __restrict__ W, float* __restrict__ Mm) {
  const int i = blockIdx.x;
  const int j = threadIdx.x;
  float s = 0.f;
#pragma unroll 8
  for (int k = 0; k < D; ++k) s = fmaf(A[k * D + i], A[k * D + j], s);
  const float diag = (i == j) ? 1.f : 0.f;
  const float w = 0.95f * diag - s + B[i * D + j] - B[j * D + i];
  W[i * D + j] = w;
  Mm[i * D + j] = 2.f * diag - w;
}

// ---------------------------------------------------------------------------
// Kernel 2: Winv = Mm^{-1}, register-resident Gauss-Jordan (no pivoting; the
// symmetric part of Mm is >= 1.05 I).
// ---------------------------------------------------------------------------
__global__ __launch_bounds__(1024) void inv_kernel(const float* __restrict__ Mm,
                                                   float* __restrict__ Winv) {
  __shared__ float rowbuf[2 * D];
  __shared__ float colbuf[D];
  const int t = threadIdx.x;
  const int c = t & 255;
  const int rb = t >> 8;
  const int r0 = rb * 32;
  float aug[32];
#pragma unroll
  for (int rr = 0; rr < 32; ++rr) {
    const int r = r0 + rr;
    aug[rr] = (c < D) ? Mm[r * D + c] : ((c - D == r) ? 1.f : 0.f);
  }
  for (int k = 0; k < D; ++k) {
    float rv = 0.f;
#pragma unroll
    for (int rr = 0; rr < 32; ++rr)
      if (rr == (k & 31)) rv = aug[rr];
    if (rb == (k >> 5)) rowbuf[c] = rv;
    if (c == k) {
#pragma unroll
      for (int rr = 0; rr < 32; ++rr) colbuf[r0 + rr] = aug[rr];
    }
    __syncthreads();
    const float invp = 1.f / rowbuf[k];
    const float pr = rowbuf[c] * invp;
#pragma unroll
    for (int rr = 0; rr < 32; ++rr) {
      const int r = r0 + rr;
      aug[rr] = (r == k) ? pr : fmaf(-colbuf[r], pr, aug[rr]);
    }
    __syncthreads();
  }
  if (c >= D) {
#pragma unroll
    for (int rr = 0; rr < 32; ++rr) Winv[(r0 + rr) * D + (c - D)] = aug[rr];
  }
}

// ---------------------------------------------------------------------------
// Kernel 3: fp16-split MFMA Peaceman-Rachford.
// Block = 512 thr (8 waves), 32 batch rows/wave, grid 256 (1 block/CU).
// OUT^T = M x V^T orientation: C-layout col = batch row -> lane-local update.
// A-matrix (Uw/Winv/W) staged in LDS as hi/lo f16, XOR-swizzled granules.
// B-fragments built in-register from per-lane state via v_permlane32_swap.
// State: u12 (|2z12 - u12| recurrence), bw = bias@Winv^T folded constant.
// ---------------------------------------------------------------------------
__global__ __launch_bounds__(512, 2) void mon_main(
    const float* __restrict__ x, const float* __restrict__ Uw,
    const float* __restrict__ ub, const float* __restrict__ Wg,
    const float* __restrict__ Winvg, float* __restrict__ out) {

  __shared__ u32x4 AH[2048];   // 32 KB: hi f16, [row][16 granules of 8 feats]
  __shared__ u32x4 AL[2048];   // 32 KB: lo f16
  __shared__ u32x2 BW[8192];   // 64 KB: bw (ft 2..3) f16-pairs, [row][32 gran]
  __shared__ float UB[D];

  const int t = threadIdx.x;
  const int w = t >> 6;
  const int l = t & 63;
  const int l5 = l & 31;
  const int hi5 = l >> 5;
  const int rg = blockIdx.x * 256 + w * 32 + l5;

  const int base_g = l5 * 16 + (hi5 ^ (l5 & 7));  // swizzled A granule base
  const int bw_base = (w * 32 + l5) * 32;
  const int bw_m = (2 * hi5) ^ l5;
  const int vub = hi5 * 16;
  const float* xr = x + (size_t)rg * D + hi5 * 8;

  f32x16 acc[4];
  float u12[4][16];   // PR state (also reused for bias / z / z@W^T)
  float bwr[2][16];   // bw for ft 0..1 (f32, registers)

  auto stageAB = [&](const float* __restrict__ M) {
#pragma unroll
    for (int it = 0; it < 4; ++it) {
      const int G = t + it * 512;
      const int i = G >> 4, g = G & 15;
      const float* src = M + i * D + g * 8;
      f32x4 a = *(const f32x4*)src;
      f32x4 b = *(const f32x4*)(src + 4);
      unsigned h0, l0_, h1, l1_, h2_, l2_, h3, l3_;
      split2(a[0], a[1], h0, l0_);
      split2(a[2], a[3], h1, l1_);
      split2(b[0], b[1], h2_, l2_);
      split2(b[2], b[3], h3, l3_);
      const int pg = g ^ (i & 7);
      AH[i * 16 + pg] = (u32x4){h0, h1, h2_, h3};
      AL[i * 16 + pg] = (u32x4){l0_, l1_, l2_, l3_};
    }
  };

  // one Winv/W multiply pass: acc = A_staged @ (state in u12)^T, 3-term split
  auto mfma_pass = [&]() {
#pragma unroll
    for (int ft = 0; ft < 4; ++ft) acc[ft] = zero16();
#pragma unroll
    for (int h2 = 0; h2 < 2; ++h2) {
      u32x4 fH[4], fL[4];
#pragma unroll
      for (int jj = 0; jj < 2; ++jj) {
        const int jt = 2 * h2 + jj;
        unsigned oh[8], ol[8];
#pragma unroll
        for (int e2 = 0; e2 < 8; ++e2)
          split2(u12[jt][2 * e2], u12[jt][2 * e2 + 1], oh[e2], ol[e2]);
#pragma unroll
        for (int e2h = 0; e2h < 2; ++e2h) {
          const int ktl = 2 * jj + e2h;
#pragma unroll
          for (int b = 0; b < 2; ++b) {
            auto rh = __builtin_amdgcn_permlane32_swap(oh[4 * e2h + b], oh[4 * e2h + 2 + b], false, false);
            auto rl = __builtin_amdgcn_permlane32_swap(ol[4 * e2h + b], ol[4 * e2h + 2 + b], false, false);
            fH[ktl][b] = rh[0]; fH[ktl][2 + b] = rh[1];
            fL[ktl][b] = rl[0]; fL[ktl][2 + b] = rl[1];
          }
        }
      }
#pragma unroll
      for (int ktl = 0; ktl < 4; ++ktl) {
        const int kt = 4 * h2 + ktl;
        const int gx = base_g ^ (2 * kt);
        u32x4 a_[4];
#pragma unroll
        for (int ft = 0; ft < 4; ++ft) a_[ft] = AH[ft * 512 + gx];
#pragma unroll
        for (int ft = 0; ft < 4; ++ft) acc[ft] = mm(a_[ft], fH[ktl], acc[ft]);
#pragma unroll
        for (int ft = 0; ft < 4; ++ft) acc[ft] = mm(a_[ft], fL[ktl], acc[ft]);
#pragma unroll
        for (int ft = 0; ft < 4; ++ft) a_[ft] = AL[ft * 512 + gx];
#pragma unroll
        for (int ft = 0; ft < 4; ++ft) acc[ft] = mm(a_[ft], fH[ktl], acc[ft]);
      }
    }
  };

  // x @ Uw^T pass (Uw staged): B-frags straight from global x (no swap needed)
  auto x_pass = [&]() {
#pragma unroll
    for (int ft = 0; ft < 4; ++ft) acc[ft] = zero16();
#pragma unroll
    for (int kt = 0; kt < 8; ++kt) {
      f32x4 xa = *(const f32x4*)(xr + kt * 16);
      f32x4 xb = *(const f32x4*)(xr + kt * 16 + 4);
      unsigned h0, l0_, h1, l1_, h2_, l2_, h3, l3_;
      split2(xa[0], xa[1], h0, l0_);
      split2(xa[2], xa[3], h1, l1_);
      split2(xb[0], xb[1], h2_, l2_);
      split2(xb[2], xb[3], h3, l3_);
      u32x4 fh = (u32x4){h0, h1, h2_, h3};
      u32x4 fl = (u32x4){l0_, l1_, l2_, l3_};
      const int gx = base_g ^ (2 * kt);
      u32x4 a_[4];
#pragma unroll
      for (int ft = 0; ft < 4; ++ft) a_[ft] = AH[ft * 512 + gx];
#pragma unroll
      for (int ft = 0; ft < 4; ++ft) acc[ft] = mm(a_[ft], fh, acc[ft]);
#pragma unroll
      for (int ft = 0; ft < 4; ++ft) acc[ft] = mm(a_[ft], fl, acc[ft]);
#pragma unroll
      for (int ft = 0; ft < 4; ++ft) a_[ft] = AL[ft * 512 + gx];
#pragma unroll
      for (int ft = 0; ft < 4; ++ft) acc[ft] = mm(a_[ft], fh, acc[ft]);
    }
  };

  // fetch bw for (ft,e2) pair -> b0,b1
  auto get_bw = [&](int ft, int e2, float &b0, float &b1) {
    if (ft < 2) {
      b0 = bwr[ft][2 * e2];
      b1 = bwr[ft][2 * e2 + 1];
    } else {
      const int c = 16 * (ft - 2) + (e2 & 1) + 4 * (e2 >> 1);
      u32x2 g = BW[bw_base + (c ^ bw_m)];
      b0 = unpack_hl(g[0]);
      b1 = unpack_hl(g[1]);
    }
  };

  // ---- Phase A: bias = x @ Uw^T + ub  (into u12)
  stageAB(Uw);
  if (t < D) UB[t] = ub[t];
  __syncthreads();
  x_pass();
#pragma unroll
  for (int ft = 0; ft < 4; ++ft)
#pragma unroll
    for (int e2 = 0; e2 < 8; ++e2) {
      const int i0 = 32 * ft + 2 * (e2 & 1) + 8 * (e2 >> 1);
      f32x2 ubp = *(const f32x2*)((const char*)UB + vub + 4 * i0);
      u12[ft][2 * e2] = acc[ft][2 * e2] + ubp[0];
      u12[ft][2 * e2 + 1] = acc[ft][2 * e2 + 1] + ubp[1];
    }
  __syncthreads();
  stageAB(Winvg);
  __syncthreads();

  // ---- Phase A2 (= PR iteration 1, u12_1 = 0): bw = bias @ Winv^T
  mfma_pass();  // reads u12 (= bias) -> acc = bw
#pragma unroll
  for (int ft = 0; ft < 2; ++ft)
#pragma unroll
    for (int e = 0; e < 16; ++e) bwr[ft][e] = acc[ft][e];
#pragma unroll
  for (int ft = 2; ft < 4; ++ft)
#pragma unroll
    for (int e2 = 0; e2 < 8; ++e2) {
      const int c = 16 * (ft - 2) + (e2 & 1) + 4 * (e2 >> 1);
      BW[bw_base + (c ^ bw_m)] =
          (u32x2){pack_hl(acc[ft][2 * e2]), pack_hl(acc[ft][2 * e2 + 1])};
    }
  // t1 = 2*bw - 0 ; u12_2 = |t1|
#pragma unroll
  for (int ft = 0; ft < 4; ++ft)
#pragma unroll
    for (int e = 0; e < 16; ++e) u12[ft][e] = __builtin_fabsf(2.f * acc[ft][e]);

  // ---- PR iterations 2..49 (48 full steps, no barriers needed)
#pragma unroll 1
  for (int it = 0; it < 48; ++it) {
    mfma_pass();
#pragma unroll
    for (int ft = 0; ft < 4; ++ft)
#pragma unroll
      for (int e2 = 0; e2 < 8; ++e2) {
        float b0, b1;
        get_bw(ft, e2, b0, b1);
        float t0 = 2.f * (acc[ft][2 * e2] + b0) - u12[ft][2 * e2];
        float t1 = 2.f * (acc[ft][2 * e2 + 1] + b1) - u12[ft][2 * e2 + 1];
        u12[ft][2 * e2] = __builtin_fabsf(t0);
        u12[ft][2 * e2 + 1] = __builtin_fabsf(t1);
      }
  }

  // ---- Iteration 50: z = relu(2*z12 - u12) (into u12)
  mfma_pass();
#pragma unroll
  for (int ft = 0; ft < 4; ++ft)
#pragma unroll
    for (int e2 = 0; e2 < 8; ++e2) {
      float b0, b1;
      get_bw(ft, e2, b0, b1);
      float t0 = 2.f * (acc[ft][2 * e2] + b0) - u12[ft][2 * e2];
      float t1 = 2.f * (acc[ft][2 * e2 + 1] + b1) - u12[ft][2 * e2 + 1];
      u12[ft][2 * e2] = fmaxf(t0, 0.f);
      u12[ft][2 * e2 + 1] = fmaxf(t1, 0.f);
    }

  // ---- Phase C1: aw = z @ W^T
  __syncthreads();
  stageAB(Wg);
  __syncthreads();
  mfma_pass();  // reads u12 (= z) -> acc = z @ W^T
#pragma unroll
  for (int ft = 0; ft < 4; ++ft)
#pragma unroll
    for (int e = 0; e < 16; ++e) u12[ft][e] = acc[ft][e];  // z dead; keep aw

  // ---- Phase C2: out = relu(x@Uw^T + ub + aw)
  __syncthreads();
  stageAB(Uw);
  __syncthreads();
  x_pass();
  float* op = out + (size_t)rg * D;
#pragma unroll
  for (int ft = 0; ft < 4; ++ft)
#pragma unroll
    for (int e2 = 0; e2 < 8; ++e2) {
      const int i0 = 32 * ft + 2 * (e2 & 1) + 8 * (e2 >> 1);
      f32x2 ubp = *(const f32x2*)((const char*)UB + vub + 4 * i0);
      float o0 = fmaxf(acc[ft][2 * e2] + ubp[0] + u12[ft][2 * e2], 0.f);
      float o1 = fmaxf(acc[ft][2 * e2 + 1] + ubp[1] + u12[ft][2 * e2 + 1], 0.f);
      *(f32x2*)(op + i0 + 4 * hi5) = (f32x2){o0, o1};
    }
}

// ---------------------------------------------------------------------------
extern "C" void kernel_launch(void* const* d_in, const int* in_sizes, int n_in,
                              void* d_out, int out_size, void* d_ws, size_t ws_size,
                              hipStream_t stream) {
  const float* x = (const float*)d_in[0];
  const float* Uw = (const float*)d_in[1];
  const float* ub = (const float*)d_in[2];
  const float* A = (const float*)d_in[3];
  const float* B = (const float*)d_in[4];
  float* out = (float*)d_out;

  float* W = (float*)d_ws;        // 64 KB
  float* Mm = W + D * D;          // 64 KB
  float* Winv = W + 2 * D * D;    // 64 KB

  wmat_kernel<<<D, D, 0, stream>>>(A, B, W, Mm);
  inv_kernel<<<1, 1024, 0, stream>>>(Mm, Winv);

  const int batch = in_sizes[0] / D;  // 65536
  mon_main<<<batch / 256, 512, 0, stream>>>(x, Uw, ub, W, Winv, out);
}

// Round 4
// 779.484 us; speedup vs baseline: 2.8502x; 1.6658x over previous
//
#include <hip/hip_runtime.h>

#define D 128

typedef __attribute__((ext_vector_type(2))) float f32x2;
typedef __attribute__((ext_vector_type(4))) float f32x4;
typedef __attribute__((ext_vector_type(16))) float f32x16;
typedef __attribute__((ext_vector_type(8))) _Float16 f16x8;
typedef __attribute__((ext_vector_type(2))) __fp16 fp16v2;
typedef __attribute__((ext_vector_type(4))) unsigned int u32x4;

// split f32 pair -> packed f16 hi-pair + lo-pair
__device__ __forceinline__ void split2(float a, float b, unsigned &hi, unsigned &lo) {
  fp16v2 h = __builtin_amdgcn_cvt_pkrtz(a, b);
  float ra = a - (float)h[0];
  float rb = b - (float)h[1];
  fp16v2 lv = __builtin_amdgcn_cvt_pkrtz(ra, rb);
  hi = __builtin_bit_cast(unsigned, h);
  lo = __builtin_bit_cast(unsigned, lv);
}

__device__ __forceinline__ f32x16 mm(u32x4 a, u32x4 b, f32x16 c) {
  return __builtin_amdgcn_mfma_f32_32x32x16_f16(
      __builtin_bit_cast(f16x8, a), __builtin_bit_cast(f16x8, b), c, 0, 0, 0);
}

__device__ __forceinline__ f32x16 zero16() {
  f32x16 z;
#pragma unroll
  for (int e = 0; e < 16; ++e) z[e] = 0.f;
  return z;
}

// ---------------------------------------------------------------------------
// Kernel 1: W = 0.95 I - A^T A + B - B^T ;  Mm = 2 I - W
// ---------------------------------------------------------------------------
__global__ void wmat_kernel(const float* __restrict__ A, const float* __restrict__ B,
                            float* __restrict__ W, float* __restrict__ Mm) {
  const int i = blockIdx.x;
  const int j = threadIdx.x;
  float s = 0.f;
#pragma unroll 8
  for (int k = 0; k < D; ++k) s = fmaf(A[k * D + i], A[k * D + j], s);
  const float diag = (i == j) ? 1.f : 0.f;
  const float w = 0.95f * diag - s + B[i * D + j] - B[j * D + i];
  W[i * D + j] = w;
  Mm[i * D + j] = 2.f * diag - w;
}

// ---------------------------------------------------------------------------
// Kernel 2: Winv = Mm^{-1}, register-resident Gauss-Jordan (no pivoting).
// ---------------------------------------------------------------------------
__global__ __launch_bounds__(1024) void inv_kernel(const float* __restrict__ Mm,
                                                   float* __restrict__ Winv) {
  __shared__ float rowbuf[2 * D];
  __shared__ float colbuf[D];
  const int t = threadIdx.x;
  const int c = t & 255;
  const int rb = t >> 8;
  const int r0 = rb * 32;
  float aug[32];
#pragma unroll
  for (int rr = 0; rr < 32; ++rr) {
    const int r = r0 + rr;
    aug[rr] = (c < D) ? Mm[r * D + c] : ((c - D == r) ? 1.f : 0.f);
  }
  for (int k = 0; k < D; ++k) {
    float rv = 0.f;
#pragma unroll
    for (int rr = 0; rr < 32; ++rr)
      if (rr == (k & 31)) rv = aug[rr];
    if (rb == (k >> 5)) rowbuf[c] = rv;
    if (c == k) {
#pragma unroll
      for (int rr = 0; rr < 32; ++rr) colbuf[r0 + rr] = aug[rr];
    }
    __syncthreads();
    const float invp = 1.f / rowbuf[k];
    const float pr = rowbuf[c] * invp;
#pragma unroll
    for (int rr = 0; rr < 32; ++rr) {
      const int r = r0 + rr;
      aug[rr] = (r == k) ? pr : fmaf(-colbuf[r], pr, aug[rr]);
    }
    __syncthreads();
  }
  if (c >= D) {
#pragma unroll
    for (int rr = 0; rr < 32; ++rr) Winv[(r0 + rr) * D + (c - D)] = aug[rr];
  }
}

// ---------------------------------------------------------------------------
// Kernel 3: fp16-split MFMA Peaceman-Rachford.
// Block = 256 thr (4 waves), 64 rows/wave (2 colsets of 32), grid 256,
// 1 block/CU, 1 wave/SIMD -> 512 unified regs/wave (kills round-3 spills).
// Colsets interleaved per (ft,kt) so A hi/lo LDS reads are shared by both.
// bw (bias@Winv^T): colset0 in regs (64 f32), colset1 in LDS (swizzled f32x2).
// No barriers inside the 50-iteration loop.
// ---------------------------------------------------------------------------
__global__ __launch_bounds__(256, 1) void mon_main(
    const float* __restrict__ x, const float* __restrict__ Uw,
    const float* __restrict__ ub, const float* __restrict__ Wg,
    const float* __restrict__ Winvg, float* __restrict__ out) {

  __shared__ u32x4 AH[2048];   // 32 KB hi f16, [row][16 granules], XOR swizzle
  __shared__ u32x4 AL[2048];   // 32 KB lo f16
  __shared__ f32x2 BW1[8192];  // 64 KB bw colset1, [row128][64 pair-granules]
  __shared__ float UB[D];

  const int t = threadIdx.x;
  const int w = t >> 6;
  const int l = t & 63;
  const int l5 = l & 31;
  const int hi5 = l >> 5;
  const int rg0 = blockIdx.x * 256 + w * 64 + l5;        // colset0 row
  const int rg1 = rg0 + 32;                              // colset1 row

  const int base_g = l5 * 16 + (hi5 ^ (l5 & 7));  // swizzled A granule base
  const int b1base = (w * 32 + l5) * 64;          // BW1 row base (granules)
  const int bw_m = 2 * (l5 & 7);                  // BW1 granule swizzle
  const int vub = hi5 * 16;
  const float* xr0 = x + (size_t)rg0 * D + hi5 * 8;
  const float* xr1 = x + (size_t)rg1 * D + hi5 * 8;

  f32x16 acc[2][4];
  float u12[2][4][16];   // PR state per colset (also bias / z / aw)
  float bwr[4][16];      // bw colset0 (f32, registers)

  auto stageAB = [&](const float* __restrict__ M) {
#pragma unroll
    for (int it = 0; it < 8; ++it) {
      const int G = t + it * 256;
      const int i = G >> 4, g = G & 15;
      const float* src = M + i * D + g * 8;
      f32x4 a = *(const f32x4*)src;
      f32x4 b = *(const f32x4*)(src + 4);
      unsigned h0, l0_, h1, l1_, h2_, l2_, h3, l3_;
      split2(a[0], a[1], h0, l0_);
      split2(a[2], a[3], h1, l1_);
      split2(b[0], b[1], h2_, l2_);
      split2(b[2], b[3], h3, l3_);
      const int pg = g ^ (i & 7);
      AH[i * 16 + pg] = (u32x4){h0, h1, h2_, h3};
      AL[i * 16 + pg] = (u32x4){l0_, l1_, l2_, l3_};
    }
  };

  // acc[c] += A_staged @ (u12[c])^T for both colsets, 3-term fp16 split
  auto mfma_pass = [&]() {
#pragma unroll
    for (int c = 0; c < 2; ++c)
#pragma unroll
      for (int ft = 0; ft < 4; ++ft) acc[c][ft] = zero16();
#pragma unroll
    for (int h2 = 0; h2 < 2; ++h2) {
      u32x4 fH[2][4], fL[2][4];
#pragma unroll
      for (int c = 0; c < 2; ++c)
#pragma unroll
        for (int jj = 0; jj < 2; ++jj) {
          const int jt = 2 * h2 + jj;
          unsigned oh[8], ol[8];
#pragma unroll
          for (int e2 = 0; e2 < 8; ++e2)
            split2(u12[c][jt][2 * e2], u12[c][jt][2 * e2 + 1], oh[e2], ol[e2]);
#pragma unroll
          for (int e2h = 0; e2h < 2; ++e2h) {
            const int ktl = 2 * jj + e2h;
#pragma unroll
            for (int b = 0; b < 2; ++b) {
              auto rh = __builtin_amdgcn_permlane32_swap(oh[4 * e2h + b], oh[4 * e2h + 2 + b], false, false);
              auto rl = __builtin_amdgcn_permlane32_swap(ol[4 * e2h + b], ol[4 * e2h + 2 + b], false, false);
              fH[c][ktl][b] = rh[0]; fH[c][ktl][2 + b] = rh[1];
              fL[c][ktl][b] = rl[0]; fL[c][ktl][2 + b] = rl[1];
            }
          }
        }
#pragma unroll
      for (int ktl = 0; ktl < 4; ++ktl) {
        const int kt = 4 * h2 + ktl;
        const int gx = base_g ^ (2 * kt);
#pragma unroll
        for (int ft = 0; ft < 4; ++ft) {
          const u32x4 ah = AH[ft * 512 + gx];
          const u32x4 al = AL[ft * 512 + gx];
#pragma unroll
          for (int c = 0; c < 2; ++c) {
            acc[c][ft] = mm(ah, fH[c][ktl], acc[c][ft]);
            acc[c][ft] = mm(ah, fL[c][ktl], acc[c][ft]);
            acc[c][ft] = mm(al, fH[c][ktl], acc[c][ft]);
          }
        }
      }
    }
  };

  // acc[c] = x_rows(c) @ A_staged^T  (B-frags straight from global x)
  auto x_pass = [&](int c, const float* __restrict__ xrc) {
#pragma unroll
    for (int ft = 0; ft < 4; ++ft) acc[c][ft] = zero16();
#pragma unroll
    for (int kt = 0; kt < 8; ++kt) {
      f32x4 xa = *(const f32x4*)(xrc + kt * 16);
      f32x4 xb = *(const f32x4*)(xrc + kt * 16 + 4);
      unsigned h0, l0_, h1, l1_, h2_, l2_, h3, l3_;
      split2(xa[0], xa[1], h0, l0_);
      split2(xa[2], xa[3], h1, l1_);
      split2(xb[0], xb[1], h2_, l2_);
      split2(xb[2], xb[3], h3, l3_);
      u32x4 fh = (u32x4){h0, h1, h2_, h3};
      u32x4 fl = (u32x4){l0_, l1_, l2_, l3_};
      const int gx = base_g ^ (2 * kt);
#pragma unroll
      for (int ft = 0; ft < 4; ++ft) {
        const u32x4 ah = AH[ft * 512 + gx];
        const u32x4 al = AL[ft * 512 + gx];
        acc[c][ft] = mm(ah, fh, acc[c][ft]);
        acc[c][ft] = mm(ah, fl, acc[c][ft]);
        acc[c][ft] = mm(al, fh, acc[c][ft]);
      }
    }
  };

  auto get_bw = [&](int c, int ft, int e2, float &b0, float &b1) {
    if (c == 0) {
      b0 = bwr[ft][2 * e2];
      b1 = bwr[ft][2 * e2 + 1];
    } else {
      const int g2 = (16 * ft + (e2 & 1) + 4 * (e2 >> 1) + 2 * hi5) ^ bw_m;
      f32x2 g = BW1[b1base + g2];
      b0 = g[0];
      b1 = g[1];
    }
  };

  // ---- Phase A: bias = x @ Uw^T + ub  (into u12)
  stageAB(Uw);
  if (t < D) UB[t] = ub[t];
  __syncthreads();
  x_pass(0, xr0);
  x_pass(1, xr1);
#pragma unroll
  for (int c = 0; c < 2; ++c)
#pragma unroll
    for (int ft = 0; ft < 4; ++ft)
#pragma unroll
      for (int e2 = 0; e2 < 8; ++e2) {
        const int i0 = 32 * ft + 2 * (e2 & 1) + 8 * (e2 >> 1);
        f32x2 ubp = *(const f32x2*)((const char*)UB + vub + 4 * i0);
        u12[c][ft][2 * e2] = acc[c][ft][2 * e2] + ubp[0];
        u12[c][ft][2 * e2 + 1] = acc[c][ft][2 * e2 + 1] + ubp[1];
      }
  __syncthreads();
  stageAB(Winvg);
  __syncthreads();

  // ---- Phase A2 (= PR iteration 1, u12_1 = 0): bw = bias @ Winv^T
  mfma_pass();
#pragma unroll
  for (int ft = 0; ft < 4; ++ft)
#pragma unroll
    for (int e = 0; e < 16; ++e) bwr[ft][e] = acc[0][ft][e];
#pragma unroll
  for (int ft = 0; ft < 4; ++ft)
#pragma unroll
    for (int e2 = 0; e2 < 8; ++e2) {
      const int g2 = (16 * ft + (e2 & 1) + 4 * (e2 >> 1) + 2 * hi5) ^ bw_m;
      BW1[b1base + g2] = (f32x2){acc[1][ft][2 * e2], acc[1][ft][2 * e2 + 1]};
    }
#pragma unroll
  for (int c = 0; c < 2; ++c)
#pragma unroll
    for (int ft = 0; ft < 4; ++ft)
#pragma unroll
      for (int e = 0; e < 16; ++e)
        u12[c][ft][e] = __builtin_fabsf(2.f * acc[c][ft][e]);

  // ---- PR iterations 2..49 (48 full steps, no barriers)
#pragma unroll 1
  for (int it = 0; it < 48; ++it) {
    mfma_pass();
#pragma unroll
    for (int c = 0; c < 2; ++c)
#pragma unroll
      for (int ft = 0; ft < 4; ++ft)
#pragma unroll
        for (int e2 = 0; e2 < 8; ++e2) {
          float b0, b1;
          get_bw(c, ft, e2, b0, b1);
          float t0 = 2.f * (acc[c][ft][2 * e2] + b0) - u12[c][ft][2 * e2];
          float t1 = 2.f * (acc[c][ft][2 * e2 + 1] + b1) - u12[c][ft][2 * e2 + 1];
          u12[c][ft][2 * e2] = __builtin_fabsf(t0);
          u12[c][ft][2 * e2 + 1] = __builtin_fabsf(t1);
        }
  }

  // ---- Iteration 50: z = relu(2*z12 - u12)
  mfma_pass();
#pragma unroll
  for (int c = 0; c < 2; ++c)
#pragma unroll
    for (int ft = 0; ft < 4; ++ft)
#pragma unroll
      for (int e2 = 0; e2 < 8; ++e2) {
        float b0, b1;
        get_bw(c, ft, e2, b0, b1);
        float t0 = 2.f * (acc[c][ft][2 * e2] + b0) - u12[c][ft][2 * e2];
        float t1 = 2.f * (acc[c][ft][2 * e2 + 1] + b1) - u12[c][ft][2 * e2 + 1];
        u12[c][ft][2 * e2] = fmaxf(t0, 0.f);
        u12[c][ft][2 * e2 + 1] = fmaxf(t1, 0.f);
      }

  // ---- Phase C1: aw = z @ W^T
  __syncthreads();
  stageAB(Wg);
  __syncthreads();
  mfma_pass();
#pragma unroll
  for (int c = 0; c < 2; ++c)
#pragma unroll
    for (int ft = 0; ft < 4; ++ft)
#pragma unroll
      for (int e = 0; e < 16; ++e) u12[c][ft][e] = acc[c][ft][e];  // keep aw

  // ---- Phase C2: out = relu(x@Uw^T + ub + aw)
  __syncthreads();
  stageAB(Uw);
  __syncthreads();
  x_pass(0, xr0);
  x_pass(1, xr1);
  float* op0 = out + (size_t)rg0 * D;
  float* op1 = out + (size_t)rg1 * D;
#pragma unroll
  for (int c = 0; c < 2; ++c) {
    float* op = c ? op1 : op0;
#pragma unroll
    for (int ft = 0; ft < 4; ++ft)
#pragma unroll
      for (int e2 = 0; e2 < 8; ++e2) {
        const int i0 = 32 * ft + 2 * (e2 & 1) + 8 * (e2 >> 1);
        f32x2 ubp = *(const f32x2*)((const char*)UB + vub + 4 * i0);
        float o0 = fmaxf(acc[c][ft][2 * e2] + ubp[0] + u12[c][ft][2 * e2], 0.f);
        float o1 = fmaxf(acc[c][ft][2 * e2 + 1] + ubp[1] + u12[c][ft][2 * e2 + 1], 0.f);
        *(f32x2*)(op + i0 + 4 * hi5) = (f32x2){o0, o1};
      }
  }
}

// ---------------------------------------------------------------------------
extern "C" void kernel_launch(void* const* d_in, const int* in_sizes, int n_in,
                              void* d_out, int out_size, void* d_ws, size_t ws_size,
                              hipStream_t stream) {
  const float* x = (const float*)d_in[0];
  const float* Uw = (const float*)d_in[1];
  const float* ub = (const float*)d_in[2];
  const float* A = (const float*)d_in[3];
  const float* B = (const float*)d_in[4];
  float* out = (float*)d_out;

  float* W = (float*)d_ws;        // 64 KB
  float* Mm = W + D * D;          // 64 KB
  float* Winv = W + 2 * D * D;    // 64 KB

  wmat_kernel<<<D, D, 0, stream>>>(A, B, W, Mm);
  inv_kernel<<<1, 1024, 0, stream>>>(Mm, Winv);

  const int batch = in_sizes[0] / D;  // 65536
  mon_main<<<batch / 256, 256, 0, stream>>>(x, Uw, ub, W, Winv, out);
}